// Round 3
// baseline (768.641 us; speedup 1.0000x reference)
//
#include <hip/hip_runtime.h>
#include <math.h>

using u16 = unsigned short;
using u32 = unsigned int;

typedef __attribute__((ext_vector_type(8))) short short8;   // 8 x bf16 (4 VGPRs)
typedef __attribute__((ext_vector_type(4))) float float4v;  // MFMA C/D

#define S_LEN 4032   // 9*16*28
#define DIM   1536
#define NH    12
#define HD    128
#define F_DIM 9
#define H_DIM 16
#define W_DIM 28

__device__ __forceinline__ float b2f(u16 v) {
  return __uint_as_float(((u32)v) << 16);
}
__device__ __forceinline__ u16 f2bf(float f) {
  u32 u = __float_as_uint(f);
  u32 r = (u + 0x7FFFu + ((u >> 16) & 1u)) >> 16;  // RNE
  return (u16)r;
}

// async global->LDS, 16B per lane; LDS dst must be wave-uniform base + lane*16
__device__ __forceinline__ void gld16(const void* g, void* l) {
  __builtin_amdgcn_global_load_lds(
      (const __attribute__((address_space(1))) void*)g,
      (__attribute__((address_space(3))) void*)l, 16, 0, 0);
}

// ---------------------------------------------------------------------------
// f32 -> bf16 cast (vectorized: float4 in, ushort4 out). n4 = n/4.
// ---------------------------------------------------------------------------
__global__ void __launch_bounds__(256) cast_f32_bf16(
    const float* __restrict__ s, u16* __restrict__ d, int n4)
{
  int i = blockIdx.x * 256 + threadIdx.x;
  if (i < n4) {
    const float4 v = ((const float4*)s)[i];
    ushort4 o;
    o.x = f2bf(v.x); o.y = f2bf(v.y); o.z = f2bf(v.z); o.w = f2bf(v.w);
    ((ushort4*)d)[i] = o;
  }
}

// ---------------------------------------------------------------------------
// GEMM: Out[m,n] = sum_k A[m,k] * W[n,k] + bias[n]   (bf16 in, bf16/f32 out)
// 128x128 tile / block, 4 waves (2x2 of 64x64), BK=64, 16x16x32 bf16 MFMA.
// ---------------------------------------------------------------------------
template <bool F32OUT>
__device__ __forceinline__ void gemm_core(
    const u16* __restrict__ A, const u16* __restrict__ Bw,
    const float* __restrict__ bias, void* __restrict__ OutV,
    int bm, int bn)
{
  __shared__ u16 As[128 * 64];
  __shared__ u16 Bs[128 * 64];
  const int tid  = threadIdx.x;
  const int wave = tid >> 6, lane = tid & 63;
  const int quad = lane >> 4, l15 = lane & 15;
  const int wm = wave >> 1, wn = wave & 1;

  float4v acc[4][4] = {};

  const int arow = lane >> 3;        // 0..7 row within 8-row segment
  const int acol = (lane & 7) * 8;   // element offset in K

  for (int kt = 0; kt < DIM; kt += 64) {
#pragma unroll
    for (int c = 0; c < 4; ++c) {
      int seg = wave * 4 + c;        // 16 segments of 8 rows x 128B
      int row = seg * 8 + arow;
      int ga = bm + row; if (ga > S_LEN - 1) ga = S_LEN - 1;  // clamp tail rows
      gld16(&A[(size_t)ga * DIM + kt + acol], &As[seg * 512]);
      gld16(&Bw[(size_t)(bn + row) * DIM + kt + acol], &Bs[seg * 512]);
    }
    __syncthreads();
#pragma unroll
    for (int ks = 0; ks < 64; ks += 32) {
      short8 af[4], bf[4];
#pragma unroll
      for (int mt = 0; mt < 4; ++mt)
        af[mt] = *(const short8*)&As[(wm * 64 + mt * 16 + l15) * 64 + ks + quad * 8];
#pragma unroll
      for (int nt = 0; nt < 4; ++nt)
        bf[nt] = *(const short8*)&Bs[(wn * 64 + nt * 16 + l15) * 64 + ks + quad * 8];
#pragma unroll
      for (int mt = 0; mt < 4; ++mt)
#pragma unroll
        for (int nt = 0; nt < 4; ++nt)
          acc[mt][nt] = __builtin_amdgcn_mfma_f32_16x16x32_bf16(af[mt], bf[nt], acc[mt][nt], 0, 0, 0);
    }
    __syncthreads();
  }

  // epilogue: C row = quad*4+r, col = lane&15
#pragma unroll
  for (int mt = 0; mt < 4; ++mt) {
    const int row = bm + wm * 64 + mt * 16 + quad * 4;
#pragma unroll
    for (int nt = 0; nt < 4; ++nt) {
      const int col = bn + wn * 64 + nt * 16 + l15;
      const float bv = bias[col];
#pragma unroll
      for (int r = 0; r < 4; ++r) {
        float v = acc[mt][nt][r] + bv;
        if (row + r < S_LEN) {
          if (F32OUT) ((float*)OutV)[(size_t)(row + r) * DIM + col] = v;
          else        ((u16*)OutV)[(size_t)(row + r) * DIM + col] = f2bf(v);
        }
      }
    }
  }
}

__global__ void __launch_bounds__(256) gemm_qkv(
    const u16* __restrict__ X,
    const u16* __restrict__ Wq, const u16* __restrict__ Wk, const u16* __restrict__ Wv,
    const float* __restrict__ bq, const float* __restrict__ bk, const float* __restrict__ bv,
    u16* __restrict__ Qb, u16* __restrict__ Kb, u16* __restrict__ Vb)
{
  const int z = blockIdx.z;
  const u16* B    = (z == 0) ? Wq : (z == 1) ? Wk : Wv;
  const float* bi = (z == 0) ? bq : (z == 1) ? bk : bv;
  u16* O          = (z == 0) ? Qb : (z == 1) ? Kb : Vb;
  gemm_core<false>(X, B, bi, O, blockIdx.y * 128, blockIdx.x * 128);
}

__global__ void __launch_bounds__(256) gemm_wo(
    const u16* __restrict__ A, const u16* __restrict__ Wo,
    const float* __restrict__ bo, float* __restrict__ Out)
{
  gemm_core<true>(A, Wo, bo, Out, blockIdx.y * 128, blockIdx.x * 128);
}

// ---------------------------------------------------------------------------
// RMS (sumsq computed in-block over full 1536) + 3-axis RoPE, in place on Q,K.
// One block per sequence position; 256 threads x 6 elements (3 rotary pairs).
// Gains and rope tables are f32 inputs.
// ---------------------------------------------------------------------------
__global__ void __launch_bounds__(256) rms_rope(
    u16* Q, u16* K,
    const float* __restrict__ gq, const float* __restrict__ gk,
    const float* __restrict__ cf, const float* __restrict__ sf,
    const float* __restrict__ ch, const float* __restrict__ sh,
    const float* __restrict__ cw, const float* __restrict__ sw)
{
  __shared__ float red[2][4];
  const int s = blockIdx.x;
  const int t = threadIdx.x;
  const int wave = t >> 6, lane = t & 63;
  const size_t rowb = (size_t)s * DIM + t * 6;

  u16 qv[6], kv[6];
#pragma unroll
  for (int j = 0; j < 6; ++j) { qv[j] = Q[rowb + j]; kv[j] = K[rowb + j]; }

  float sq = 0.f, sk = 0.f;
#pragma unroll
  for (int j = 0; j < 6; ++j) {
    float a = b2f(qv[j]); sq += a * a;
    float b = b2f(kv[j]); sk += b * b;
  }
#pragma unroll
  for (int m = 1; m < 64; m <<= 1) {
    sq += __shfl_xor(sq, m, 64);
    sk += __shfl_xor(sk, m, 64);
  }
  if (lane == 0) { red[0][wave] = sq; red[1][wave] = sk; }
  __syncthreads();
  const float tq = red[0][0] + red[0][1] + red[0][2] + red[0][3];
  const float tk = red[1][0] + red[1][1] + red[1][2] + red[1][3];
  const float scq = rsqrtf(tq * (1.0f / DIM) + 1e-6f);
  const float sck = rsqrtf(tk * (1.0f / DIM) + 1e-6f);

  const int f  = s / (H_DIM * W_DIM);
  const int hh = (s / W_DIM) % H_DIM;
  const int w  = s % W_DIM;

#pragma unroll
  for (int j = 0; j < 3; ++j) {
    const int pi = t * 3 + j;       // global pair index 0..767
    const int c = pi & 63;          // rotary pair within head (C=64)
    float co, si;
    if (c < 22)      { co = cf[f * 22 + c];        si = sf[f * 22 + c]; }
    else if (c < 43) { co = ch[hh * 21 + c - 22];  si = sh[hh * 21 + c - 22]; }
    else             { co = cw[w * 21 + c - 43];   si = sw[w * 21 + c - 43]; }
    const int gi = 2 * pi;          // == head*128 + 2*c
    const size_t base = (size_t)s * DIM + gi;
    {
      float e = b2f(qv[2 * j])     * scq * gq[gi];
      float o = b2f(qv[2 * j + 1]) * scq * gq[gi + 1];
      Q[base]     = f2bf(e * co - o * si);
      Q[base + 1] = f2bf(e * si + o * co);
    }
    {
      float e = b2f(kv[2 * j])     * sck * gk[gi];
      float o = b2f(kv[2 * j + 1]) * sck * gk[gi + 1];
      K[base]     = f2bf(e * co - o * si);
      K[base + 1] = f2bf(e * si + o * co);
    }
  }
}

// ---------------------------------------------------------------------------
// V transpose: Vt[d][s] = V[s][d]  (bf16), 64x64 LDS tiles.
// ---------------------------------------------------------------------------
__global__ void __launch_bounds__(256) transpose_v(
    const u16* __restrict__ V, u16* __restrict__ Vt)
{
  __shared__ u16 tile[64][65];
  const int s0 = blockIdx.x * 64, d0 = blockIdx.y * 64;
  const int t = threadIdx.x;
#pragma unroll
  for (int i = 0; i < 16; ++i) {
    int idx = t + i * 256; int rr = idx >> 6, cc = idx & 63;
    tile[rr][cc] = V[(size_t)(s0 + rr) * DIM + d0 + cc];
  }
  __syncthreads();
#pragma unroll
  for (int i = 0; i < 16; ++i) {
    int idx = t + i * 256; int rr = idx >> 6, cc = idx & 63;
    Vt[(size_t)(d0 + rr) * S_LEN + s0 + cc] = tile[cc][rr];
  }
}

// ---------------------------------------------------------------------------
// Flash attention: block = (64 q-rows, 1 head), 4 waves x 16 q-rows.
// K-tile = 32 keys. Scores via 16x16x32 MFMA, online softmax (log2 domain),
// P: C-layout -> LDS -> A-layout (fenced), PV via MFMA against LDS V^T tile.
// ---------------------------------------------------------------------------
__global__ void __launch_bounds__(256) attn_kernel(
    const u16* __restrict__ rq, const u16* __restrict__ rk,
    const u16* __restrict__ vt, u16* __restrict__ ao)
{
  __shared__ u16 Ks[32 * 128];    // [key][d]  8KB
  __shared__ u16 Vs[128 * 32];    // [d][key]  8KB
  __shared__ u16 Ps[4][16 * 32];  // per-wave P tile
  const int h  = blockIdx.y;
  const int qb = blockIdx.x * 64;
  const int tid = threadIdx.x, wave = tid >> 6, lane = tid & 63;
  const int quad = lane >> 4, l15 = lane & 15;
  const int q0 = qb + wave * 16;

  short8 qf[4];
#pragma unroll
  for (int c = 0; c < 4; ++c)
    qf[c] = *(const short8*)&rq[(size_t)(q0 + l15) * DIM + h * HD + c * 32 + quad * 8];

  float4v o[8] = {};
  float m_[4] = {-1e30f, -1e30f, -1e30f, -1e30f};
  float l_[4] = {0.f, 0.f, 0.f, 0.f};

  const float SC = 0.08838834764831845f * 1.4426950408889634f;  // rsqrt(128)*log2(e)

  const int krow = lane >> 4, kc = l15 * 8;        // K staging: 4 rows/seg x 256B
  const int vrow = lane >> 2, vc = (lane & 3) * 8; // V staging: 16 rows/seg x 64B

  for (int kt = 0; kt < S_LEN; kt += 32) {
#pragma unroll
    for (int c = 0; c < 2; ++c) {
      int seg = wave * 2 + c;
      gld16(&rk[(size_t)(kt + seg * 4 + krow) * DIM + h * HD + kc], &Ks[seg * 512]);
      gld16(&vt[(size_t)(h * HD + seg * 16 + vrow) * S_LEN + kt + vc], &Vs[seg * 512]);
    }
    __syncthreads();   // drains vmcnt: staging complete

    float4v sc[2] = {};
#pragma unroll
    for (int st = 0; st < 2; ++st)
#pragma unroll
      for (int c = 0; c < 4; ++c) {
        short8 kf = *(const short8*)&Ks[(st * 16 + l15) * 128 + c * 32 + quad * 8];
        sc[st] = __builtin_amdgcn_mfma_f32_16x16x32_bf16(qf[c], kf, sc[st], 0, 0, 0);
      }

    float alpha[4];
#pragma unroll
    for (int r = 0; r < 4; ++r) {
      float s0 = sc[0][r] * SC, s1 = sc[1][r] * SC;
      float mx = fmaxf(s0, s1);
      mx = fmaxf(mx, __shfl_xor(mx, 1, 64));
      mx = fmaxf(mx, __shfl_xor(mx, 2, 64));
      mx = fmaxf(mx, __shfl_xor(mx, 4, 64));
      mx = fmaxf(mx, __shfl_xor(mx, 8, 64));
      float nm = fmaxf(m_[r], mx);
      float al = exp2f(m_[r] - nm);
      m_[r] = nm;
      float p0 = exp2f(s0 - nm), p1 = exp2f(s1 - nm);
      sc[0][r] = p0; sc[1][r] = p1;
      float rs = p0 + p1;
      rs += __shfl_xor(rs, 1, 64);
      rs += __shfl_xor(rs, 2, 64);
      rs += __shfl_xor(rs, 4, 64);
      rs += __shfl_xor(rs, 8, 64);
      l_[r] = l_[r] * al + rs;
      alpha[r] = al;
    }
#pragma unroll
    for (int ct = 0; ct < 8; ++ct)
#pragma unroll
      for (int r = 0; r < 4; ++r) o[ct][r] *= alpha[r];

    // P: C-layout (row=quad*4+r, col=l15) -> LDS row-major [16][32]
#pragma unroll
    for (int st = 0; st < 2; ++st)
#pragma unroll
      for (int r = 0; r < 4; ++r)
        Ps[wave][(quad * 4 + r) * 32 + st * 16 + l15] = f2bf(sc[st][r]);

    // Order the same-wave LDS write->read (compiler + lgkmcnt fence).
    __threadfence_block();

    // A-layout read: m=l15, k=quad*8+j
    short8 pf = *(const short8*)&Ps[wave][l15 * 32 + quad * 8];
#pragma unroll
    for (int ct = 0; ct < 8; ++ct) {
      short8 vf = *(const short8*)&Vs[(ct * 16 + l15) * 32 + quad * 8];
      o[ct] = __builtin_amdgcn_mfma_f32_16x16x32_bf16(pf, vf, o[ct], 0, 0, 0);
    }
    __syncthreads();   // all waves done reading Ks/Vs before next staging
  }

  float inv[4];
#pragma unroll
  for (int r = 0; r < 4; ++r) inv[r] = (l_[r] > 0.f) ? (1.0f / l_[r]) : 0.f;
#pragma unroll
  for (int ct = 0; ct < 8; ++ct)
#pragma unroll
    for (int r = 0; r < 4; ++r) {
      int row = q0 + quad * 4 + r;
      ao[(size_t)row * DIM + h * HD + ct * 16 + l15] = f2bf(o[ct][r] * inv[r]);
    }
}

// ---------------------------------------------------------------------------
extern "C" void kernel_launch(void* const* d_in, const int* in_sizes, int n_in,
                              void* d_out, int out_size, void* d_ws, size_t ws_size,
                              hipStream_t stream) {
  const float* x  = (const float*)d_in[0];
  const float* Wq = (const float*)d_in[1];
  const float* bq = (const float*)d_in[2];
  const float* Wk = (const float*)d_in[3];
  const float* bk = (const float*)d_in[4];
  const float* Wv = (const float*)d_in[5];
  const float* bv = (const float*)d_in[6];
  const float* Wo = (const float*)d_in[7];
  const float* bo = (const float*)d_in[8];
  const float* gq = (const float*)d_in[9];
  const float* gk = (const float*)d_in[10];
  const float* cf = (const float*)d_in[11];
  const float* sf = (const float*)d_in[12];
  const float* ch = (const float*)d_in[13];
  const float* sh = (const float*)d_in[14];
  const float* cw = (const float*)d_in[15];
  const float* sw = (const float*)d_in[16];

  char* ws = (char*)d_ws;
  const size_t sz  = (size_t)S_LEN * DIM * 2;  // 12.39 MB per bf16 activation
  const size_t wsz = (size_t)DIM * DIM * 2;    // 4.72 MB per bf16 weight
  u16* Xb  = (u16*)(ws);               // x bf16; reused as Vt after gemm_qkv
  u16* Qb  = (u16*)(ws + sz);          // becomes rq after rms_rope; reused as Ao
  u16* Kb  = (u16*)(ws + 2 * sz);      // becomes rk
  u16* Vb  = (u16*)(ws + 3 * sz);
  u16* Wqb = (u16*)(ws + 4 * sz);      // reused as Wo-bf16 after gemm_qkv
  u16* Wkb = (u16*)(ws + 4 * sz + wsz);
  u16* Wvb = (u16*)(ws + 4 * sz + 2 * wsz);
  u16* Vt  = Xb;
  u16* Ao  = Qb;  // attn block (q,h) is sole reader of the rq region it overwrites

  const int nX = S_LEN * DIM / 4;  // 1548288
  const int nW = DIM * DIM / 4;    // 589824
  cast_f32_bf16<<<(nX + 255) / 256, 256, 0, stream>>>(x,  Xb,  nX);
  cast_f32_bf16<<<(nW + 255) / 256, 256, 0, stream>>>(Wq, Wqb, nW);
  cast_f32_bf16<<<(nW + 255) / 256, 256, 0, stream>>>(Wk, Wkb, nW);
  cast_f32_bf16<<<(nW + 255) / 256, 256, 0, stream>>>(Wv, Wvb, nW);

  gemm_qkv<<<dim3(12, 32, 3), 256, 0, stream>>>(Xb, Wqb, Wkb, Wvb, bq, bk, bv, Qb, Kb, Vb);

  cast_f32_bf16<<<(nW + 255) / 256, 256, 0, stream>>>(Wo, Wqb, nW);  // Wqb := Wo bf16

  rms_rope<<<S_LEN, 256, 0, stream>>>(Qb, Kb, gq, gk, cf, sf, ch, sh, cw, sw);
  transpose_v<<<dim3(63, 24), 256, 0, stream>>>(Vb, Vt);
  attn_kernel<<<dim3(63, 12), 256, 0, stream>>>(Qb, Kb, Vt, Ao);
  gemm_wo<<<dim3(12, 32), 256, 0, stream>>>(Ao, Wqb, bo, (float*)d_out);
}